// Round 1
// baseline (450.331 us; speedup 1.0000x reference)
//
#include <hip/hip_runtime.h>
#include <cmath>

#define NEG_SLOPE 0.2f

// ---------------- GEMM: Y[N,128] = X[N,128] @ W[128,128], fp32 ----------------
__global__ __launch_bounds__(256) void gemm128(const float* __restrict__ X,
                                               const float* __restrict__ W,
                                               float* __restrict__ Y, int nrows)
{
    __shared__ float xt[32][128];
    int t = threadIdx.x;
    int r0 = blockIdx.x * 32;
    const float4* X4 = (const float4*)X;
    float4* xt4 = (float4*)&xt[0][0];
#pragma unroll
    for (int j = 0; j < 4; ++j) {
        int idx = t + 256 * j;            // 0..1023
        int rr = idx >> 5, cc = idx & 31; // row, col-quad
        int gr = r0 + rr;
        float4 v = make_float4(0.f, 0.f, 0.f, 0.f);
        if (gr < nrows) v = X4[gr * 32 + cc];
        xt4[idx] = v;
    }
    __syncthreads();
    int cq = t & 31;   // col quad: cols cq*4..cq*4+3
    int rg = t >> 5;   // row group: rows rg*4..rg*4+3
    float4 a0 = make_float4(0,0,0,0), a1 = a0, a2 = a0, a3 = a0;
    const float4* W4 = (const float4*)W;
#pragma unroll 4
    for (int k = 0; k < 128; ++k) {
        float4 w = W4[k * 32 + cq];
        float x0 = xt[rg*4+0][k];
        float x1 = xt[rg*4+1][k];
        float x2 = xt[rg*4+2][k];
        float x3 = xt[rg*4+3][k];
        a0.x += w.x*x0; a0.y += w.y*x0; a0.z += w.z*x0; a0.w += w.w*x0;
        a1.x += w.x*x1; a1.y += w.y*x1; a1.z += w.z*x1; a1.w += w.w*x1;
        a2.x += w.x*x2; a2.y += w.y*x2; a2.z += w.z*x2; a2.w += w.w*x2;
        a3.x += w.x*x3; a3.y += w.y*x3; a3.z += w.z*x3; a3.w += w.w*x3;
    }
    float4* Y4 = (float4*)Y;
    int r = r0 + rg * 4;
    if (r + 0 < nrows) Y4[(r+0)*32 + cq] = a0;
    if (r + 1 < nrows) Y4[(r+1)*32 + cq] = a1;
    if (r + 2 < nrows) Y4[(r+2)*32 + cq] = a2;
    if (r + 3 < nrows) Y4[(r+3)*32 + cq] = a3;
}

// -------- attention coefficients: el[n,h] = sum_d feat[n,h,d]*al[h,d] --------
__global__ __launch_bounds__(256) void attn_coef(const float* __restrict__ feat,
                                                 const float* __restrict__ al,
                                                 const float* __restrict__ ar,
                                                 float* __restrict__ el,
                                                 float* __restrict__ er, int nnodes)
{
    int i = blockIdx.x * blockDim.x + threadIdx.x;
    if (i >= nnodes * 4) return;
    int n = i >> 2, h = i & 3;
    const float4* f4 = (const float4*)(feat + (size_t)n * 128 + h * 32);
    const float4* a4 = (const float4*)(al + h * 32);
    const float4* b4 = (const float4*)(ar + h * 32);
    float sl = 0.f, sr = 0.f;
#pragma unroll
    for (int j = 0; j < 8; ++j) {
        float4 f = f4[j], a = a4[j], b = b4[j];
        sl += f.x*a.x + f.y*a.y + f.z*a.z + f.w*a.w;
        sr += f.x*b.x + f.y*b.y + f.z*b.z + f.w*b.w;
    }
    el[i] = sl;
    er[i] = sr;
}

// ---------------- CSR build: histogram, scan, scatter ----------------
__global__ __launch_bounds__(256) void hist_kernel(const int* __restrict__ dst,
                                                   int* __restrict__ counts, int ne)
{
    int i = blockIdx.x * blockDim.x + threadIdx.x;
    if (i < ne) atomicAdd(&counts[dst[i]], 1);
}

__global__ __launch_bounds__(1024) void scan_block(const int* __restrict__ cnt,
                                                   int* __restrict__ loc,
                                                   int* __restrict__ bsum,
                                                   int nvals, int total)
{
    __shared__ int tmp[1024];
    int t = threadIdx.x;
    int i = blockIdx.x * 1024 + t;
    int v = (i < nvals) ? cnt[i] : 0;
    tmp[t] = v;
    __syncthreads();
    for (int off = 1; off < 1024; off <<= 1) {
        int x = (t >= off) ? tmp[t - off] : 0;
        __syncthreads();
        tmp[t] += x;
        __syncthreads();
    }
    if (i < total) loc[i] = tmp[t] - v;           // exclusive within block
    if (t == 1023) bsum[blockIdx.x] = tmp[1023];  // block total
}

__global__ void scan_tops(const int* __restrict__ bsum, int* __restrict__ bout, int nb)
{
    int t = threadIdx.x; // 64 threads, one wave
    int v = (t < nb) ? bsum[t] : 0;
    int inc = v;
#pragma unroll
    for (int off = 1; off < 64; off <<= 1) {
        int x = __shfl_up(inc, off);
        if (t >= off) inc += x;
    }
    if (t < nb) bout[t] = inc - v;
}

__global__ __launch_bounds__(1024) void scan_add(const int* __restrict__ loc,
                                                 const int* __restrict__ bout,
                                                 int* __restrict__ offs,
                                                 int* __restrict__ curs,
                                                 int total, int nnodes)
{
    int i = blockIdx.x * 1024 + threadIdx.x;
    if (i >= total) return;
    int o = loc[i] + bout[blockIdx.x];
    offs[i] = o;
    if (i < nnodes) curs[i] = o;
}

__global__ __launch_bounds__(256) void scatter_kernel(const int* __restrict__ src,
                                                      const int* __restrict__ dst,
                                                      int* __restrict__ curs,
                                                      int* __restrict__ ssrc, int ne)
{
    int i = blockIdx.x * blockDim.x + threadIdx.x;
    if (i >= ne) return;
    int d = dst[i];
    int p = atomicAdd(&curs[d], 1);
    ssrc[p] = src[i];
}

// ---------------- per-destination softmax + aggregation, 1 wave per node ----------------
// LAYER 1: out[n,128] = elu(sum_e a*feat[src] + b)
// LAYER 2: out[n,32]  = mean_h(sum_e a*feat[src] + b)
template<int LAYER>
__global__ __launch_bounds__(256) void aggregate(const float* __restrict__ feat,
                                                 const float* __restrict__ el,
                                                 const float* __restrict__ er,
                                                 const int* __restrict__ offs,
                                                 const int* __restrict__ ssrc,
                                                 const float* __restrict__ bias,
                                                 float* __restrict__ out, int nnodes)
{
    int gw = (int)((blockIdx.x * (size_t)blockDim.x + threadIdx.x) >> 6);
    int lane = threadIdx.x & 63;
    if (gw >= nnodes) return;
    int beg = offs[gw], end = offs[gw + 1];
    const float4* el4p = (const float4*)el;
    float4 er4 = ((const float4*)er)[gw];

    // --- pass 1: softmax denominators (lane-parallel over edges) ---
    float d0 = 0.f, d1 = 0.f, d2 = 0.f, d3 = 0.f;
    for (int i = beg + lane; i < end; i += 64) {
        int s = ssrc[i];
        float4 e4 = el4p[s];
        float e;
        e = e4.x + er4.x; d0 += __expf(fmaxf(e, 0.f) + NEG_SLOPE * fminf(e, 0.f));
        e = e4.y + er4.y; d1 += __expf(fmaxf(e, 0.f) + NEG_SLOPE * fminf(e, 0.f));
        e = e4.z + er4.z; d2 += __expf(fmaxf(e, 0.f) + NEG_SLOPE * fminf(e, 0.f));
        e = e4.w + er4.w; d3 += __expf(fmaxf(e, 0.f) + NEG_SLOPE * fminf(e, 0.f));
    }
#pragma unroll
    for (int off = 32; off; off >>= 1) {
        d0 += __shfl_xor(d0, off);
        d1 += __shfl_xor(d1, off);
        d2 += __shfl_xor(d2, off);
        d3 += __shfl_xor(d3, off);
    }
    float inv0 = d0 > 0.f ? 1.f / d0 : 0.f;
    float inv1 = d1 > 0.f ? 1.f / d1 : 0.f;
    float inv2 = d2 > 0.f ? 1.f / d2 : 0.f;
    float inv3 = d3 > 0.f ? 1.f / d3 : 0.f;

    // --- pass 2: weighted accumulation; lane owns dims (2*lane, 2*lane+1) ---
    int h = lane >> 4;
    float erh  = h == 0 ? er4.x : h == 1 ? er4.y : h == 2 ? er4.z : er4.w;
    float invh = h == 0 ? inv0  : h == 1 ? inv1  : h == 2 ? inv2  : inv3;
    float accx = 0.f, accy = 0.f;
    const float2* f2 = (const float2*)feat;
    for (int i = beg; i < end; ++i) {
        int s = ssrc[i];
        float4 e4 = el4p[s];
        float elh = h == 0 ? e4.x : h == 1 ? e4.y : h == 2 ? e4.z : e4.w;
        float e = elh + erh;
        float a = __expf(fmaxf(e, 0.f) + NEG_SLOPE * fminf(e, 0.f)) * invh;
        float2 f = f2[(size_t)s * 64 + lane];
        accx += f.x * a;
        accy += f.y * a;
    }

    int c = lane * 2;
    if (LAYER == 1) {
        float v0 = accx + bias[c];
        float v1 = accy + bias[c + 1];
        v0 = v0 > 0.f ? v0 : expm1f(v0);
        v1 = v1 > 0.f ? v1 : expm1f(v1);
        ((float2*)out)[(size_t)gw * 64 + lane] = make_float2(v0, v1);
    } else {
        float v0 = accx + bias[c];
        float v1 = accy + bias[c + 1];
        v0 += __shfl_xor(v0, 16); v0 += __shfl_xor(v0, 32);
        v1 += __shfl_xor(v1, 16); v1 += __shfl_xor(v1, 32);
        if (lane < 16)
            ((float2*)out)[(size_t)gw * 16 + lane] = make_float2(v0 * 0.25f, v1 * 0.25f);
    }
}

template __global__ void aggregate<1>(const float*, const float*, const float*,
                                      const int*, const int*, const float*, float*, int);
template __global__ void aggregate<2>(const float*, const float*, const float*,
                                      const int*, const int*, const float*, float*, int);

// ---------------- launcher ----------------
extern "C" void kernel_launch(void* const* d_in, const int* in_sizes, int n_in,
                              void* d_out, int out_size, void* d_ws, size_t ws_size,
                              hipStream_t stream)
{
    const float* X   = (const float*)d_in[0];
    const int*   src = (const int*)d_in[1];
    const int*   dst = (const int*)d_in[2];
    const float* W1  = (const float*)d_in[3];
    const float* al1 = (const float*)d_in[4];
    const float* ar1 = (const float*)d_in[5];
    const float* b1  = (const float*)d_in[6];
    const float* W2  = (const float*)d_in[7];
    const float* al2 = (const float*)d_in[8];
    const float* ar2 = (const float*)d_in[9];
    const float* b2  = (const float*)d_in[10];
    float* out = (float*)d_out;

    const int N = in_sizes[0] / 128;
    const int E = in_sizes[1];
    const int SB = (N + 1 + 1023) / 1024;

    size_t off = 0;
    char* base = (char*)d_ws;
    auto alloc = [&](size_t bytes) -> void* {
        void* p = base + off;
        off += (bytes + 255) & ~(size_t)255;
        return p;
    };
    float* feat   = (float*)alloc((size_t)N * 128 * 4);
    float* hbuf   = (float*)alloc((size_t)N * 128 * 4);
    float* el     = (float*)alloc((size_t)N * 4 * 4);
    float* er     = (float*)alloc((size_t)N * 4 * 4);
    int*   counts = (int*)alloc((size_t)N * 4);
    int*   offs   = (int*)alloc((size_t)(N + 1) * 4);
    int*   curs   = (int*)alloc((size_t)N * 4);
    int*   ssrc   = (int*)alloc((size_t)E * 4);
    int*   loc    = (int*)alloc((size_t)SB * 1024 * 4);
    int*   bsum   = (int*)alloc(64 * 4);
    int*   bout   = (int*)alloc(64 * 4);
    (void)ws_size; (void)n_in; (void)out_size;

    hipMemsetAsync(counts, 0, (size_t)N * 4, stream);

    // layer 1 feat + coefficients
    gemm128<<<(N + 31) / 32, 256, 0, stream>>>(X, W1, feat, N);
    attn_coef<<<(N * 4 + 255) / 256, 256, 0, stream>>>(feat, al1, ar1, el, er, N);

    // CSR by destination (shared by both layers)
    hist_kernel<<<(E + 255) / 256, 256, 0, stream>>>(dst, counts, E);
    scan_block<<<SB, 1024, 0, stream>>>(counts, loc, bsum, N, N + 1);
    scan_tops<<<1, 64, 0, stream>>>(bsum, bout, SB);
    scan_add<<<SB, 1024, 0, stream>>>(loc, bout, offs, curs, N + 1, N);
    scatter_kernel<<<(E + 255) / 256, 256, 0, stream>>>(src, dst, curs, ssrc, E);

    // layer 1 aggregation -> elu(acc + b1) = hbuf [N,128]
    aggregate<1><<<(N + 3) / 4, 256, 0, stream>>>(feat, el, er, offs, ssrc, b1, hbuf, N);

    // layer 2
    gemm128<<<(N + 31) / 32, 256, 0, stream>>>(hbuf, W2, feat, N);
    attn_coef<<<(N * 4 + 255) / 256, 256, 0, stream>>>(feat, al2, ar2, el, er, N);
    aggregate<2><<<(N + 3) / 4, 256, 0, stream>>>(feat, el, er, offs, ssrc, b2, out, N);
}

// Round 2
// 313.256 us; speedup vs baseline: 1.4376x; 1.4376x over previous
//
#include <hip/hip_runtime.h>
#include <cmath>

#define NEG_SLOPE 0.2f

// ---------------- GEMM: Y[N,128] = X[N,128] @ W[128,128], fp32 ----------------
__global__ __launch_bounds__(256) void gemm128(const float* __restrict__ X,
                                               const float* __restrict__ W,
                                               float* __restrict__ Y, int nrows)
{
    __shared__ float xt[32][128];
    int t = threadIdx.x;
    int r0 = blockIdx.x * 32;
    const float4* X4 = (const float4*)X;
    float4* xt4 = (float4*)&xt[0][0];
#pragma unroll
    for (int j = 0; j < 4; ++j) {
        int idx = t + 256 * j;            // 0..1023
        int rr = idx >> 5, cc = idx & 31; // row, col-quad
        int gr = r0 + rr;
        float4 v = make_float4(0.f, 0.f, 0.f, 0.f);
        if (gr < nrows) v = X4[gr * 32 + cc];
        xt4[idx] = v;
    }
    __syncthreads();
    int cq = t & 31;   // col quad: cols cq*4..cq*4+3
    int rg = t >> 5;   // row group: rows rg*4..rg*4+3
    float4 a0 = make_float4(0,0,0,0), a1 = a0, a2 = a0, a3 = a0;
    const float4* W4 = (const float4*)W;
#pragma unroll 4
    for (int k = 0; k < 128; ++k) {
        float4 w = W4[k * 32 + cq];
        float x0 = xt[rg*4+0][k];
        float x1 = xt[rg*4+1][k];
        float x2 = xt[rg*4+2][k];
        float x3 = xt[rg*4+3][k];
        a0.x += w.x*x0; a0.y += w.y*x0; a0.z += w.z*x0; a0.w += w.w*x0;
        a1.x += w.x*x1; a1.y += w.y*x1; a1.z += w.z*x1; a1.w += w.w*x1;
        a2.x += w.x*x2; a2.y += w.y*x2; a2.z += w.z*x2; a2.w += w.w*x2;
        a3.x += w.x*x3; a3.y += w.y*x3; a3.z += w.z*x3; a3.w += w.w*x3;
    }
    float4* Y4 = (float4*)Y;
    int r = r0 + rg * 4;
    if (r + 0 < nrows) Y4[(r+0)*32 + cq] = a0;
    if (r + 1 < nrows) Y4[(r+1)*32 + cq] = a1;
    if (r + 2 < nrows) Y4[(r+2)*32 + cq] = a2;
    if (r + 3 < nrows) Y4[(r+3)*32 + cq] = a3;
}

// -------- attention coefficients: el[n,h] = sum_d feat[n,h,d]*al[h,d] --------
__global__ __launch_bounds__(256) void attn_coef(const float* __restrict__ feat,
                                                 const float* __restrict__ al,
                                                 const float* __restrict__ ar,
                                                 float* __restrict__ el,
                                                 float* __restrict__ er, int nnodes)
{
    int i = blockIdx.x * blockDim.x + threadIdx.x;
    if (i >= nnodes * 4) return;
    int n = i >> 2, h = i & 3;
    const float4* f4 = (const float4*)(feat + (size_t)n * 128 + h * 32);
    const float4* a4 = (const float4*)(al + h * 32);
    const float4* b4 = (const float4*)(ar + h * 32);
    float sl = 0.f, sr = 0.f;
#pragma unroll
    for (int j = 0; j < 8; ++j) {
        float4 f = f4[j], a = a4[j], b = b4[j];
        sl += f.x*a.x + f.y*a.y + f.z*a.z + f.w*a.w;
        sr += f.x*b.x + f.y*b.y + f.z*b.z + f.w*b.w;
    }
    el[i] = sl;
    er[i] = sr;
}

// ---------------- CSR build: histogram, scan, scatter ----------------
__global__ __launch_bounds__(256) void hist_kernel(const int* __restrict__ dst,
                                                   int* __restrict__ counts, int ne)
{
    int i = blockIdx.x * blockDim.x + threadIdx.x;
    if (i < ne) atomicAdd(&counts[dst[i]], 1);
}

__global__ __launch_bounds__(1024) void scan_block(const int* __restrict__ cnt,
                                                   int* __restrict__ loc,
                                                   int* __restrict__ bsum,
                                                   int nvals, int total)
{
    __shared__ int tmp[1024];
    int t = threadIdx.x;
    int i = blockIdx.x * 1024 + t;
    int v = (i < nvals) ? cnt[i] : 0;
    tmp[t] = v;
    __syncthreads();
    for (int off = 1; off < 1024; off <<= 1) {
        int x = (t >= off) ? tmp[t - off] : 0;
        __syncthreads();
        tmp[t] += x;
        __syncthreads();
    }
    if (i < total) loc[i] = tmp[t] - v;           // exclusive within block
    if (t == 1023) bsum[blockIdx.x] = tmp[1023];  // block total
}

__global__ void scan_tops(const int* __restrict__ bsum, int* __restrict__ bout, int nb)
{
    int t = threadIdx.x; // 64 threads, one wave
    int v = (t < nb) ? bsum[t] : 0;
    int inc = v;
#pragma unroll
    for (int off = 1; off < 64; off <<= 1) {
        int x = __shfl_up(inc, off);
        if (t >= off) inc += x;
    }
    if (t < nb) bout[t] = inc - v;
}

__global__ __launch_bounds__(1024) void scan_add(const int* __restrict__ loc,
                                                 const int* __restrict__ bout,
                                                 int* __restrict__ offs,
                                                 int* __restrict__ curs,
                                                 int total, int nnodes)
{
    int i = blockIdx.x * 1024 + threadIdx.x;
    if (i >= total) return;
    int o = loc[i] + bout[blockIdx.x];
    offs[i] = o;
    if (i < nnodes) curs[i] = o;
}

__global__ __launch_bounds__(256) void scatter_kernel(const int* __restrict__ src,
                                                      const int* __restrict__ dst,
                                                      int* __restrict__ curs,
                                                      int* __restrict__ ssrc, int ne)
{
    int i = blockIdx.x * blockDim.x + threadIdx.x;
    if (i >= ne) return;
    int d = dst[i];
    int p = atomicAdd(&curs[d], 1);
    ssrc[p] = src[i];
}

// ---------------- per-destination softmax + aggregation, 1 wave per node ----------------
// Single fused pass: per 64-edge chunk, lane-parallel weight computation into
// wave-private LDS, then an unrolled serial feature-gather loop whose global
// loads are mutually independent (index/weight come from LDS, not memory).
// LAYER 1: out[n,128] = elu(sum_e a*feat[src] + b)
// LAYER 2: out[n,32]  = mean_h(sum_e a*feat[src] + b)
template<int LAYER>
__global__ __launch_bounds__(256) void aggregate(const float* __restrict__ feat,
                                                 const float* __restrict__ el,
                                                 const float* __restrict__ er,
                                                 const int* __restrict__ offs,
                                                 const int* __restrict__ ssrc,
                                                 const float* __restrict__ bias,
                                                 float* __restrict__ out, int nnodes)
{
    __shared__ int   s_sh[4][64];
    __shared__ float w_sh[4][256];
    int wid  = threadIdx.x >> 6;
    int lane = threadIdx.x & 63;
    int gw = blockIdx.x * 4 + wid;
    if (gw >= nnodes) return;
    int beg = offs[gw], end = offs[gw + 1];
    float4 er4 = ((const float4*)er)[gw];
    const float4* el4 = (const float4*)el;
    const float2* f2  = (const float2*)feat;
    int h = lane >> 4;

    float accx = 0.f, accy = 0.f;
    float d0 = 0.f, d1 = 0.f, d2 = 0.f, d3 = 0.f;

    for (int cbeg = beg; cbeg < end; cbeg += 64) {
        int cnt = end - cbeg; if (cnt > 64) cnt = 64;
        // --- lane-parallel: load src idx + compute 4-head exp weights ---
        int myS = (lane < cnt) ? ssrc[cbeg + lane] : 0;
        float4 e4 = el4[myS];
        float ex0 = 0.f, ex1 = 0.f, ex2 = 0.f, ex3 = 0.f;
        if (lane < cnt) {
            float e;
            e = e4.x + er4.x; ex0 = __expf(fmaxf(e, 0.f) + NEG_SLOPE * fminf(e, 0.f));
            e = e4.y + er4.y; ex1 = __expf(fmaxf(e, 0.f) + NEG_SLOPE * fminf(e, 0.f));
            e = e4.z + er4.z; ex2 = __expf(fmaxf(e, 0.f) + NEG_SLOPE * fminf(e, 0.f));
            e = e4.w + er4.w; ex3 = __expf(fmaxf(e, 0.f) + NEG_SLOPE * fminf(e, 0.f));
            d0 += ex0; d1 += ex1; d2 += ex2; d3 += ex3;
        }
        s_sh[wid][lane] = myS;
        ((float4*)&w_sh[wid][0])[lane] = make_float4(ex0, ex1, ex2, ex3);
        // wave-private LDS: producer == consumer wave, lgkmcnt ordering suffices

        // --- serial over chunk edges; gathers independent, unrolled x4 ---
        int i = 0;
        for (; i + 4 <= cnt; i += 4) {
            int s0 = s_sh[wid][i+0], s1 = s_sh[wid][i+1];
            int s2 = s_sh[wid][i+2], s3 = s_sh[wid][i+3];
            float w0 = w_sh[wid][(i+0)*4 + h];
            float w1 = w_sh[wid][(i+1)*4 + h];
            float w2 = w_sh[wid][(i+2)*4 + h];
            float w3 = w_sh[wid][(i+3)*4 + h];
            float2 fa = f2[(size_t)s0 * 64 + lane];
            float2 fb = f2[(size_t)s1 * 64 + lane];
            float2 fc = f2[(size_t)s2 * 64 + lane];
            float2 fd = f2[(size_t)s3 * 64 + lane];
            accx += fa.x * w0; accy += fa.y * w0;
            accx += fb.x * w1; accy += fb.y * w1;
            accx += fc.x * w2; accy += fc.y * w2;
            accx += fd.x * w3; accy += fd.y * w3;
        }
        for (; i < cnt; ++i) {
            int s = s_sh[wid][i];
            float w = w_sh[wid][i*4 + h];
            float2 f = f2[(size_t)s * 64 + lane];
            accx += f.x * w; accy += f.y * w;
        }
    }

    // --- wave-reduce denominators (once) ---
#pragma unroll
    for (int off = 32; off; off >>= 1) {
        d0 += __shfl_xor(d0, off);
        d1 += __shfl_xor(d1, off);
        d2 += __shfl_xor(d2, off);
        d3 += __shfl_xor(d3, off);
    }
    float dh   = h == 0 ? d0 : h == 1 ? d1 : h == 2 ? d2 : d3;
    float invh = dh > 0.f ? 1.f / dh : 0.f;
    accx *= invh; accy *= invh;

    int c = lane * 2;
    if (LAYER == 1) {
        float v0 = accx + bias[c];
        float v1 = accy + bias[c + 1];
        v0 = v0 > 0.f ? v0 : expm1f(v0);
        v1 = v1 > 0.f ? v1 : expm1f(v1);
        ((float2*)out)[(size_t)gw * 64 + lane] = make_float2(v0, v1);
    } else {
        float v0 = accx + bias[c];
        float v1 = accy + bias[c + 1];
        v0 += __shfl_xor(v0, 16); v0 += __shfl_xor(v0, 32);
        v1 += __shfl_xor(v1, 16); v1 += __shfl_xor(v1, 32);
        if (lane < 16)
            ((float2*)out)[(size_t)gw * 16 + lane] = make_float2(v0 * 0.25f, v1 * 0.25f);
    }
}

template __global__ void aggregate<1>(const float*, const float*, const float*,
                                      const int*, const int*, const float*, float*, int);
template __global__ void aggregate<2>(const float*, const float*, const float*,
                                      const int*, const int*, const float*, float*, int);

// ---------------- launcher ----------------
extern "C" void kernel_launch(void* const* d_in, const int* in_sizes, int n_in,
                              void* d_out, int out_size, void* d_ws, size_t ws_size,
                              hipStream_t stream)
{
    const float* X   = (const float*)d_in[0];
    const int*   src = (const int*)d_in[1];
    const int*   dst = (const int*)d_in[2];
    const float* W1  = (const float*)d_in[3];
    const float* al1 = (const float*)d_in[4];
    const float* ar1 = (const float*)d_in[5];
    const float* b1  = (const float*)d_in[6];
    const float* W2  = (const float*)d_in[7];
    const float* al2 = (const float*)d_in[8];
    const float* ar2 = (const float*)d_in[9];
    const float* b2  = (const float*)d_in[10];
    float* out = (float*)d_out;

    const int N = in_sizes[0] / 128;
    const int E = in_sizes[1];
    const int SB = (N + 1 + 1023) / 1024;

    size_t off = 0;
    char* base = (char*)d_ws;
    auto alloc = [&](size_t bytes) -> void* {
        void* p = base + off;
        off += (bytes + 255) & ~(size_t)255;
        return p;
    };
    float* feat   = (float*)alloc((size_t)N * 128 * 4);
    float* hbuf   = (float*)alloc((size_t)N * 128 * 4);
    float* el     = (float*)alloc((size_t)N * 4 * 4);
    float* er     = (float*)alloc((size_t)N * 4 * 4);
    int*   counts = (int*)alloc((size_t)N * 4);
    int*   offs   = (int*)alloc((size_t)(N + 1) * 4);
    int*   curs   = (int*)alloc((size_t)N * 4);
    int*   ssrc   = (int*)alloc((size_t)E * 4);
    int*   loc    = (int*)alloc((size_t)SB * 1024 * 4);
    int*   bsum   = (int*)alloc(64 * 4);
    int*   bout   = (int*)alloc(64 * 4);
    (void)ws_size; (void)n_in; (void)out_size;

    hipMemsetAsync(counts, 0, (size_t)N * 4, stream);

    // layer 1 feat + coefficients
    gemm128<<<(N + 31) / 32, 256, 0, stream>>>(X, W1, feat, N);
    attn_coef<<<(N * 4 + 255) / 256, 256, 0, stream>>>(feat, al1, ar1, el, er, N);

    // CSR by destination (shared by both layers)
    hist_kernel<<<(E + 255) / 256, 256, 0, stream>>>(dst, counts, E);
    scan_block<<<SB, 1024, 0, stream>>>(counts, loc, bsum, N, N + 1);
    scan_tops<<<1, 64, 0, stream>>>(bsum, bout, SB);
    scan_add<<<SB, 1024, 0, stream>>>(loc, bout, offs, curs, N + 1, N);
    scatter_kernel<<<(E + 255) / 256, 256, 0, stream>>>(src, dst, curs, ssrc, E);

    // layer 1 aggregation -> elu(acc + b1) = hbuf [N,128]
    aggregate<1><<<(N + 3) / 4, 256, 0, stream>>>(feat, el, er, offs, ssrc, b1, hbuf, N);

    // layer 2
    gemm128<<<(N + 31) / 32, 256, 0, stream>>>(hbuf, W2, feat, N);
    attn_coef<<<(N * 4 + 255) / 256, 256, 0, stream>>>(feat, al2, ar2, el, er, N);
    aggregate<2><<<(N + 3) / 4, 256, 0, stream>>>(feat, el, er, offs, ssrc, b2, out, N);
}

// Round 3
// 292.550 us; speedup vs baseline: 1.5393x; 1.0708x over previous
//
#include <hip/hip_runtime.h>
#include <cmath>

#define NEG_SLOPE 0.2f

// ------- GEMM + fused attention coefficients:
//   Y[N,128] = X[N,128] @ W[128,128]
//   el[n,h] = sum_d Y[n,h*32+d]*al[h,d],  er likewise  (fused epilogue)
__global__ __launch_bounds__(256) void gemm_attn(const float* __restrict__ X,
                                                 const float* __restrict__ W,
                                                 const float* __restrict__ al,
                                                 const float* __restrict__ ar,
                                                 float* __restrict__ Y,
                                                 float* __restrict__ el,
                                                 float* __restrict__ er, int nrows)
{
    __shared__ float xt[32][128];
    int t = threadIdx.x;
    int lane = t & 63;
    int r0 = blockIdx.x * 32;
    const float4* X4 = (const float4*)X;
    float4* xt4 = (float4*)&xt[0][0];
#pragma unroll
    for (int j = 0; j < 4; ++j) {
        int idx = t + 256 * j;            // 0..1023
        int rr = idx >> 5, cc = idx & 31; // row, col-quad
        int gr = r0 + rr;
        float4 v = make_float4(0.f, 0.f, 0.f, 0.f);
        if (gr < nrows) v = X4[gr * 32 + cc];
        xt4[idx] = v;
    }
    __syncthreads();
    int cq = t & 31;   // col quad: cols cq*4..cq*4+3
    int rg = t >> 5;   // row group: rows rg*4..rg*4+3
    float4 a0 = make_float4(0,0,0,0), a1 = a0, a2 = a0, a3 = a0;
    const float4* W4 = (const float4*)W;
#pragma unroll 4
    for (int k = 0; k < 128; ++k) {
        float4 w = W4[k * 32 + cq];
        float x0 = xt[rg*4+0][k];
        float x1 = xt[rg*4+1][k];
        float x2 = xt[rg*4+2][k];
        float x3 = xt[rg*4+3][k];
        a0.x += w.x*x0; a0.y += w.y*x0; a0.z += w.z*x0; a0.w += w.w*x0;
        a1.x += w.x*x1; a1.y += w.y*x1; a1.z += w.z*x1; a1.w += w.w*x1;
        a2.x += w.x*x2; a2.y += w.y*x2; a2.z += w.z*x2; a2.w += w.w*x2;
        a3.x += w.x*x3; a3.y += w.y*x3; a3.z += w.z*x3; a3.w += w.w*x3;
    }
    float4* Y4 = (float4*)Y;
    int r = r0 + rg * 4;
    if (r + 0 < nrows) Y4[(r+0)*32 + cq] = a0;
    if (r + 1 < nrows) Y4[(r+1)*32 + cq] = a1;
    if (r + 2 < nrows) Y4[(r+2)*32 + cq] = a2;
    if (r + 3 < nrows) Y4[(r+3)*32 + cq] = a3;

    // ---- fused el/er: reduce each head's 8 column-quads across 8 lanes ----
    float4 alv = ((const float4*)al)[cq];
    float4 arv = ((const float4*)ar)[cq];
    float elv[4], erv[4];
    elv[0] = a0.x*alv.x + a0.y*alv.y + a0.z*alv.z + a0.w*alv.w;
    erv[0] = a0.x*arv.x + a0.y*arv.y + a0.z*arv.z + a0.w*arv.w;
    elv[1] = a1.x*alv.x + a1.y*alv.y + a1.z*alv.z + a1.w*alv.w;
    erv[1] = a1.x*arv.x + a1.y*arv.y + a1.z*arv.z + a1.w*arv.w;
    elv[2] = a2.x*alv.x + a2.y*alv.y + a2.z*alv.z + a2.w*alv.w;
    erv[2] = a2.x*arv.x + a2.y*arv.y + a2.z*arv.z + a2.w*arv.w;
    elv[3] = a3.x*alv.x + a3.y*alv.y + a3.z*alv.z + a3.w*alv.w;
    erv[3] = a3.x*arv.x + a3.y*arv.y + a3.z*arv.z + a3.w*arv.w;
#pragma unroll
    for (int rr = 0; rr < 4; ++rr) {
#pragma unroll
        for (int off = 1; off < 8; off <<= 1) {
            elv[rr] += __shfl_xor(elv[rr], off);
            erv[rr] += __shfl_xor(erv[rr], off);
        }
    }
    if ((lane & 7) == 0) {
        int hh = (lane & 31) >> 3;
#pragma unroll
        for (int rr = 0; rr < 4; ++rr) {
            int row = r + rr;
            if (row < nrows) {
                el[row * 4 + hh] = elv[rr];
                er[row * 4 + hh] = erv[rr];
            }
        }
    }
}

// ---------------- CSR build: histogram, scan, scatter ----------------
__global__ __launch_bounds__(256) void hist_kernel(const int* __restrict__ dst,
                                                   int* __restrict__ counts, int ne)
{
    int i = blockIdx.x * blockDim.x + threadIdx.x;
    if (i < ne) atomicAdd(&counts[dst[i]], 1);
}

__global__ __launch_bounds__(1024) void scan_block(const int* __restrict__ cnt,
                                                   int* __restrict__ loc,
                                                   int* __restrict__ bsum,
                                                   int nvals, int total)
{
    __shared__ int wsum[16];
    int t = threadIdx.x, lane = t & 63, w = t >> 6;
    int i = blockIdx.x * 1024 + t;
    int v = (i < nvals) ? cnt[i] : 0;
    int x = v;
#pragma unroll
    for (int off = 1; off < 64; off <<= 1) {
        int y = __shfl_up(x, off);
        if (lane >= off) x += y;
    }                                   // inclusive scan within wave
    if (lane == 63) wsum[w] = x;
    __syncthreads();
    if (w == 0) {
        int s = (lane < 16) ? wsum[lane] : 0;
#pragma unroll
        for (int off = 1; off < 16; off <<= 1) {
            int y = __shfl_up(s, off);
            if (lane >= off) s += y;
        }
        if (lane < 16) wsum[lane] = s;  // inclusive wave sums
    }
    __syncthreads();
    int base = (w > 0) ? wsum[w - 1] : 0;
    int incl = base + x;
    if (i < total) loc[i] = incl - v;           // exclusive within block
    if (t == 1023) bsum[blockIdx.x] = incl;     // block total
}

__global__ void scan_tops(const int* __restrict__ bsum, int* __restrict__ bout, int nb)
{
    int t = threadIdx.x; // 64 threads, one wave
    int v = (t < nb) ? bsum[t] : 0;
    int inc = v;
#pragma unroll
    for (int off = 1; off < 64; off <<= 1) {
        int x = __shfl_up(inc, off);
        if (t >= off) inc += x;
    }
    if (t < nb) bout[t] = inc - v;
}

__global__ __launch_bounds__(1024) void scan_add(const int* __restrict__ loc,
                                                 const int* __restrict__ bout,
                                                 int* __restrict__ offs,
                                                 int* __restrict__ curs,
                                                 int total, int nnodes)
{
    int i = blockIdx.x * 1024 + threadIdx.x;
    if (i >= total) return;
    int o = loc[i] + bout[blockIdx.x];
    offs[i] = o;
    if (i < nnodes) curs[i] = o;
}

__global__ __launch_bounds__(256) void scatter_kernel(const int* __restrict__ src,
                                                      const int* __restrict__ dst,
                                                      int* __restrict__ curs,
                                                      int* __restrict__ ssrc, int ne)
{
    int i = blockIdx.x * blockDim.x + threadIdx.x;
    if (i >= ne) return;
    int d = dst[i];
    int p = atomicAdd(&curs[d], 1);
    ssrc[p] = src[i];
}

// ---------------- per-destination softmax + aggregation, 1 wave per node ----------------
// Per 64-edge chunk: lane-parallel weight computation into wave-private LDS,
// then a depth-16/8/4/1 statically-unrolled gather loop — all global loads in
// a group are issued before any FMA consumes them (max MLP).
// LAYER 1: out[n,128] = elu(sum_e a*feat[src] + b)
// LAYER 2: out[n,32]  = mean_h(sum_e a*feat[src] + b)
template<int LAYER>
__global__ __launch_bounds__(256) void aggregate(const float* __restrict__ feat,
                                                 const float* __restrict__ el,
                                                 const float* __restrict__ er,
                                                 const int* __restrict__ offs,
                                                 const int* __restrict__ ssrc,
                                                 const float* __restrict__ bias,
                                                 float* __restrict__ out, int nnodes)
{
    __shared__ int   s_sh[4][64];
    __shared__ float w_sh[4][256];
    int wid  = threadIdx.x >> 6;
    int lane = threadIdx.x & 63;
    int gw = blockIdx.x * 4 + wid;
    if (gw >= nnodes) return;
    int beg = offs[gw], end = offs[gw + 1];
    float4 er4 = ((const float4*)er)[gw];
    const float4* el4 = (const float4*)el;
    const float2* f2  = (const float2*)feat;
    int h = lane >> 4;

    float accx = 0.f, accy = 0.f;
    float d0 = 0.f, d1 = 0.f, d2 = 0.f, d3 = 0.f;

    for (int cbeg = beg; cbeg < end; cbeg += 64) {
        int cnt = end - cbeg; if (cnt > 64) cnt = 64;
        // --- lane-parallel: load src idx + compute 4-head exp weights ---
        int myS = (lane < cnt) ? ssrc[cbeg + lane] : 0;
        float4 e4 = el4[myS];
        float ex0 = 0.f, ex1 = 0.f, ex2 = 0.f, ex3 = 0.f;
        if (lane < cnt) {
            float e;
            e = e4.x + er4.x; ex0 = __expf(fmaxf(e, 0.f) + NEG_SLOPE * fminf(e, 0.f));
            e = e4.y + er4.y; ex1 = __expf(fmaxf(e, 0.f) + NEG_SLOPE * fminf(e, 0.f));
            e = e4.z + er4.z; ex2 = __expf(fmaxf(e, 0.f) + NEG_SLOPE * fminf(e, 0.f));
            e = e4.w + er4.w; ex3 = __expf(fmaxf(e, 0.f) + NEG_SLOPE * fminf(e, 0.f));
            d0 += ex0; d1 += ex1; d2 += ex2; d3 += ex3;
        }
        s_sh[wid][lane] = myS;
        ((float4*)&w_sh[wid][0])[lane] = make_float4(ex0, ex1, ex2, ex3);
        // wave-private LDS: producer == consumer wave, in-order DS pipe

        // --- gather loop: static unroll, loads grouped before FMAs ---
        int i = 0;
        for (; i + 16 <= cnt; i += 16) {
            float  w[16]; float2 f[16];
#pragma unroll
            for (int j = 0; j < 16; ++j) {
                int s = s_sh[wid][i + j];
                w[j] = w_sh[wid][(i + j) * 4 + h];
                f[j] = f2[(size_t)s * 64 + lane];
            }
#pragma unroll
            for (int j = 0; j < 16; ++j) {
                accx += f[j].x * w[j];
                accy += f[j].y * w[j];
            }
        }
        for (; i + 8 <= cnt; i += 8) {
            float  w[8]; float2 f[8];
#pragma unroll
            for (int j = 0; j < 8; ++j) {
                int s = s_sh[wid][i + j];
                w[j] = w_sh[wid][(i + j) * 4 + h];
                f[j] = f2[(size_t)s * 64 + lane];
            }
#pragma unroll
            for (int j = 0; j < 8; ++j) {
                accx += f[j].x * w[j];
                accy += f[j].y * w[j];
            }
        }
        for (; i + 4 <= cnt; i += 4) {
            float  w[4]; float2 f[4];
#pragma unroll
            for (int j = 0; j < 4; ++j) {
                int s = s_sh[wid][i + j];
                w[j] = w_sh[wid][(i + j) * 4 + h];
                f[j] = f2[(size_t)s * 64 + lane];
            }
#pragma unroll
            for (int j = 0; j < 4; ++j) {
                accx += f[j].x * w[j];
                accy += f[j].y * w[j];
            }
        }
        for (; i < cnt; ++i) {
            int s = s_sh[wid][i];
            float w = w_sh[wid][i*4 + h];
            float2 f = f2[(size_t)s * 64 + lane];
            accx += f.x * w; accy += f.y * w;
        }
    }

    // --- wave-reduce denominators (once) ---
#pragma unroll
    for (int off = 32; off; off >>= 1) {
        d0 += __shfl_xor(d0, off);
        d1 += __shfl_xor(d1, off);
        d2 += __shfl_xor(d2, off);
        d3 += __shfl_xor(d3, off);
    }
    float dh   = h == 0 ? d0 : h == 1 ? d1 : h == 2 ? d2 : d3;
    float invh = dh > 0.f ? 1.f / dh : 0.f;
    accx *= invh; accy *= invh;

    int c = lane * 2;
    if (LAYER == 1) {
        float v0 = accx + bias[c];
        float v1 = accy + bias[c + 1];
        v0 = v0 > 0.f ? v0 : expm1f(v0);
        v1 = v1 > 0.f ? v1 : expm1f(v1);
        ((float2*)out)[(size_t)gw * 64 + lane] = make_float2(v0, v1);
    } else {
        float v0 = accx + bias[c];
        float v1 = accy + bias[c + 1];
        v0 += __shfl_xor(v0, 16); v0 += __shfl_xor(v0, 32);
        v1 += __shfl_xor(v1, 16); v1 += __shfl_xor(v1, 32);
        if (lane < 16)
            ((float2*)out)[(size_t)gw * 16 + lane] = make_float2(v0 * 0.25f, v1 * 0.25f);
    }
}

template __global__ void aggregate<1>(const float*, const float*, const float*,
                                      const int*, const int*, const float*, float*, int);
template __global__ void aggregate<2>(const float*, const float*, const float*,
                                      const int*, const int*, const float*, float*, int);

// ---------------- launcher ----------------
extern "C" void kernel_launch(void* const* d_in, const int* in_sizes, int n_in,
                              void* d_out, int out_size, void* d_ws, size_t ws_size,
                              hipStream_t stream)
{
    const float* X   = (const float*)d_in[0];
    const int*   src = (const int*)d_in[1];
    const int*   dst = (const int*)d_in[2];
    const float* W1  = (const float*)d_in[3];
    const float* al1 = (const float*)d_in[4];
    const float* ar1 = (const float*)d_in[5];
    const float* b1  = (const float*)d_in[6];
    const float* W2  = (const float*)d_in[7];
    const float* al2 = (const float*)d_in[8];
    const float* ar2 = (const float*)d_in[9];
    const float* b2  = (const float*)d_in[10];
    float* out = (float*)d_out;

    const int N = in_sizes[0] / 128;
    const int E = in_sizes[1];
    const int SB = (N + 1 + 1023) / 1024;

    size_t off = 0;
    char* base = (char*)d_ws;
    auto alloc = [&](size_t bytes) -> void* {
        void* p = base + off;
        off += (bytes + 255) & ~(size_t)255;
        return p;
    };
    float* feat   = (float*)alloc((size_t)N * 128 * 4);
    float* hbuf   = (float*)alloc((size_t)N * 128 * 4);
    float* el     = (float*)alloc((size_t)N * 4 * 4);
    float* er     = (float*)alloc((size_t)N * 4 * 4);
    int*   counts = (int*)alloc((size_t)N * 4);
    int*   offs   = (int*)alloc((size_t)(N + 1) * 4);
    int*   curs   = (int*)alloc((size_t)N * 4);
    int*   ssrc   = (int*)alloc((size_t)E * 4);
    int*   loc    = (int*)alloc((size_t)SB * 1024 * 4);
    int*   bsum   = (int*)alloc(64 * 4);
    int*   bout   = (int*)alloc(64 * 4);
    (void)ws_size; (void)n_in; (void)out_size;

    hipMemsetAsync(counts, 0, (size_t)N * 4, stream);

    // layer 1: GEMM + fused attention coefficients
    gemm_attn<<<(N + 31) / 32, 256, 0, stream>>>(X, W1, al1, ar1, feat, el, er, N);

    // CSR by destination (shared by both layers)
    hist_kernel<<<(E + 255) / 256, 256, 0, stream>>>(dst, counts, E);
    scan_block<<<SB, 1024, 0, stream>>>(counts, loc, bsum, N, N + 1);
    scan_tops<<<1, 64, 0, stream>>>(bsum, bout, SB);
    scan_add<<<SB, 1024, 0, stream>>>(loc, bout, offs, curs, N + 1, N);
    scatter_kernel<<<(E + 255) / 256, 256, 0, stream>>>(src, dst, curs, ssrc, E);

    // layer 1 aggregation -> elu(acc + b1) = hbuf [N,128]
    aggregate<1><<<(N + 3) / 4, 256, 0, stream>>>(feat, el, er, offs, ssrc, b1, hbuf, N);

    // layer 2
    gemm_attn<<<(N + 31) / 32, 256, 0, stream>>>(hbuf, W2, al2, ar2, feat, el, er, N);
    aggregate<2><<<(N + 3) / 4, 256, 0, stream>>>(feat, el, er, offs, ssrc, b2, out, N);
}

// Round 4
// 290.523 us; speedup vs baseline: 1.5501x; 1.0070x over previous
//
#include <hip/hip_runtime.h>
#include <cmath>

#define NEG_SLOPE 0.2f

// ------- GEMM + fused attention coefficients:
//   Y[N,128] = X[N,128] @ W[128,128]
//   el[n,h] = sum_d Y[n,h*32+d]*al[h,d],  er likewise  (fused epilogue)
__global__ __launch_bounds__(256) void gemm_attn(const float* __restrict__ X,
                                                 const float* __restrict__ W,
                                                 const float* __restrict__ al,
                                                 const float* __restrict__ ar,
                                                 float* __restrict__ Y,
                                                 float* __restrict__ el,
                                                 float* __restrict__ er, int nrows)
{
    __shared__ float xt[32][128];
    int t = threadIdx.x;
    int lane = t & 63;
    int r0 = blockIdx.x * 32;
    const float4* X4 = (const float4*)X;
    float4* xt4 = (float4*)&xt[0][0];
#pragma unroll
    for (int j = 0; j < 4; ++j) {
        int idx = t + 256 * j;            // 0..1023
        int rr = idx >> 5, cc = idx & 31; // row, col-quad
        int gr = r0 + rr;
        float4 v = make_float4(0.f, 0.f, 0.f, 0.f);
        if (gr < nrows) v = X4[gr * 32 + cc];
        xt4[idx] = v;
    }
    __syncthreads();
    int cq = t & 31;   // col quad: cols cq*4..cq*4+3
    int rg = t >> 5;   // row group: rows rg*4..rg*4+3
    float4 a0 = make_float4(0,0,0,0), a1 = a0, a2 = a0, a3 = a0;
    const float4* W4 = (const float4*)W;
#pragma unroll 4
    for (int k = 0; k < 128; ++k) {
        float4 w = W4[k * 32 + cq];
        float x0 = xt[rg*4+0][k];
        float x1 = xt[rg*4+1][k];
        float x2 = xt[rg*4+2][k];
        float x3 = xt[rg*4+3][k];
        a0.x += w.x*x0; a0.y += w.y*x0; a0.z += w.z*x0; a0.w += w.w*x0;
        a1.x += w.x*x1; a1.y += w.y*x1; a1.z += w.z*x1; a1.w += w.w*x1;
        a2.x += w.x*x2; a2.y += w.y*x2; a2.z += w.z*x2; a2.w += w.w*x2;
        a3.x += w.x*x3; a3.y += w.y*x3; a3.z += w.z*x3; a3.w += w.w*x3;
    }
    float4* Y4 = (float4*)Y;
    int r = r0 + rg * 4;
    if (r + 0 < nrows) Y4[(r+0)*32 + cq] = a0;
    if (r + 1 < nrows) Y4[(r+1)*32 + cq] = a1;
    if (r + 2 < nrows) Y4[(r+2)*32 + cq] = a2;
    if (r + 3 < nrows) Y4[(r+3)*32 + cq] = a3;

    // ---- fused el/er: reduce each head's 8 column-quads across 8 lanes ----
    float4 alv = ((const float4*)al)[cq];
    float4 arv = ((const float4*)ar)[cq];
    float elv[4], erv[4];
    elv[0] = a0.x*alv.x + a0.y*alv.y + a0.z*alv.z + a0.w*alv.w;
    erv[0] = a0.x*arv.x + a0.y*arv.y + a0.z*arv.z + a0.w*arv.w;
    elv[1] = a1.x*alv.x + a1.y*alv.y + a1.z*alv.z + a1.w*alv.w;
    erv[1] = a1.x*arv.x + a1.y*arv.y + a1.z*arv.z + a1.w*arv.w;
    elv[2] = a2.x*alv.x + a2.y*alv.y + a2.z*alv.z + a2.w*alv.w;
    erv[2] = a2.x*arv.x + a2.y*arv.y + a2.z*arv.z + a2.w*arv.w;
    elv[3] = a3.x*alv.x + a3.y*alv.y + a3.z*alv.z + a3.w*alv.w;
    erv[3] = a3.x*arv.x + a3.y*arv.y + a3.z*arv.z + a3.w*arv.w;
#pragma unroll
    for (int rr = 0; rr < 4; ++rr) {
#pragma unroll
        for (int off = 1; off < 8; off <<= 1) {
            elv[rr] += __shfl_xor(elv[rr], off);
            erv[rr] += __shfl_xor(erv[rr], off);
        }
    }
    if ((lane & 7) == 0) {
        int hh = (lane & 31) >> 3;
#pragma unroll
        for (int rr = 0; rr < 4; ++rr) {
            int row = r + rr;
            if (row < nrows) {
                el[row * 4 + hh] = elv[rr];
                er[row * 4 + hh] = erv[rr];
            }
        }
    }
}

// ---------------- CSR build: histogram, scan, scatter ----------------
__global__ __launch_bounds__(256) void hist_kernel(const int* __restrict__ dst,
                                                   int* __restrict__ counts, int ne)
{
    int i = blockIdx.x * blockDim.x + threadIdx.x;
    if (i < ne) atomicAdd(&counts[dst[i]], 1);
}

__global__ __launch_bounds__(1024) void scan_block(const int* __restrict__ cnt,
                                                   int* __restrict__ loc,
                                                   int* __restrict__ bsum,
                                                   int nvals, int total)
{
    __shared__ int wsum[16];
    int t = threadIdx.x, lane = t & 63, w = t >> 6;
    int i = blockIdx.x * 1024 + t;
    int v = (i < nvals) ? cnt[i] : 0;
    int x = v;
#pragma unroll
    for (int off = 1; off < 64; off <<= 1) {
        int y = __shfl_up(x, off);
        if (lane >= off) x += y;
    }                                   // inclusive scan within wave
    if (lane == 63) wsum[w] = x;
    __syncthreads();
    if (w == 0) {
        int s = (lane < 16) ? wsum[lane] : 0;
#pragma unroll
        for (int off = 1; off < 16; off <<= 1) {
            int y = __shfl_up(s, off);
            if (lane >= off) s += y;
        }
        if (lane < 16) wsum[lane] = s;  // inclusive wave sums
    }
    __syncthreads();
    int base = (w > 0) ? wsum[w - 1] : 0;
    int incl = base + x;
    if (i < total) loc[i] = incl - v;           // exclusive within block
    if (t == 1023) bsum[blockIdx.x] = incl;     // block total
}

__global__ void scan_tops(const int* __restrict__ bsum, int* __restrict__ bout, int nb)
{
    int t = threadIdx.x; // 64 threads, one wave
    int v = (t < nb) ? bsum[t] : 0;
    int inc = v;
#pragma unroll
    for (int off = 1; off < 64; off <<= 1) {
        int x = __shfl_up(inc, off);
        if (t >= off) inc += x;
    }
    if (t < nb) bout[t] = inc - v;
}

__global__ __launch_bounds__(1024) void scan_add(const int* __restrict__ loc,
                                                 const int* __restrict__ bout,
                                                 int* __restrict__ offs,
                                                 int* __restrict__ curs,
                                                 int total, int nnodes)
{
    int i = blockIdx.x * 1024 + threadIdx.x;
    if (i >= total) return;
    int o = loc[i] + bout[blockIdx.x];
    offs[i] = o;
    if (i < nnodes) curs[i] = o;
}

__global__ __launch_bounds__(256) void scatter_kernel(const int* __restrict__ src,
                                                      const int* __restrict__ dst,
                                                      int* __restrict__ curs,
                                                      int* __restrict__ ssrc, int ne)
{
    int i = blockIdx.x * blockDim.x + threadIdx.x;
    if (i >= ne) return;
    int d = dst[i];
    int p = atomicAdd(&curs[d], 1);
    ssrc[p] = src[i];
}

// ---------------- per-destination softmax + aggregation, 1 wave per node ----------------
// Per 64-edge chunk: lane-parallel weight computation (edge indices stay in
// registers), then gather in groups of 16 where the row index comes from
// v_readlane (SGPR, compile-time lane id) -> back-to-back load issue, true MLP.
// Pad edges have w=0, s=0 (row 0 is L1-hot), keeping results exact.
// LAYER 1: out[n,128] = elu(sum_e a*feat[src] + b)
// LAYER 2: out[n,32]  = mean_h(sum_e a*feat[src] + b)
template<int LAYER>
__global__ __launch_bounds__(256) void aggregate(const float* __restrict__ feat,
                                                 const float* __restrict__ el,
                                                 const float* __restrict__ er,
                                                 const int* __restrict__ offs,
                                                 const int* __restrict__ ssrc,
                                                 const float* __restrict__ bias,
                                                 float* __restrict__ out, int nnodes)
{
    __shared__ float w_sh[4][256];
    int wid  = threadIdx.x >> 6;
    int lane = threadIdx.x & 63;
    int gw = blockIdx.x * 4 + wid;
    if (gw >= nnodes) return;
    int beg = offs[gw], end = offs[gw + 1];
    float4 er4 = ((const float4*)er)[gw];
    const float4* el4 = (const float4*)el;
    const float2* f2  = (const float2*)feat;
    int h = lane >> 4;

    float accx = 0.f, accy = 0.f;
    float d0 = 0.f, d1 = 0.f, d2 = 0.f, d3 = 0.f;

    for (int cbeg = beg; cbeg < end; cbeg += 64) {
        int cnt = end - cbeg; if (cnt > 64) cnt = 64;
        // --- lane-parallel: load src idx + compute 4-head exp weights ---
        int myS = (lane < cnt) ? ssrc[cbeg + lane] : 0;
        float4 e4 = el4[myS];
        float ex0 = 0.f, ex1 = 0.f, ex2 = 0.f, ex3 = 0.f;
        if (lane < cnt) {
            float e;
            e = e4.x + er4.x; ex0 = __expf(fmaxf(e, 0.f) + NEG_SLOPE * fminf(e, 0.f));
            e = e4.y + er4.y; ex1 = __expf(fmaxf(e, 0.f) + NEG_SLOPE * fminf(e, 0.f));
            e = e4.z + er4.z; ex2 = __expf(fmaxf(e, 0.f) + NEG_SLOPE * fminf(e, 0.f));
            e = e4.w + er4.w; ex3 = __expf(fmaxf(e, 0.f) + NEG_SLOPE * fminf(e, 0.f));
            d0 += ex0; d1 += ex1; d2 += ex2; d3 += ex3;
        }
        ((float4*)&w_sh[wid][0])[lane] = make_float4(ex0, ex1, ex2, ex3);
        // wave-private LDS: producer == consumer wave, in-order DS pipe

        // --- gather: 4 groups of 16; index via readlane (SGPR addressing) ---
#pragma unroll
        for (int g = 0; g < 4; ++g) {
            if (g * 16 < cnt) {
                float2 f[16]; float w[16];
#pragma unroll
                for (int k = 0; k < 16; ++k) {
                    int s = __builtin_amdgcn_readlane(myS, g * 16 + k);
                    f[k] = f2[(size_t)s * 64 + lane];
                    w[k] = w_sh[wid][(g * 16 + k) * 4 + h];
                }
#pragma unroll
                for (int k = 0; k < 16; ++k) {
                    accx += f[k].x * w[k];
                    accy += f[k].y * w[k];
                }
            }
        }
    }

    // --- wave-reduce denominators (once) ---
#pragma unroll
    for (int off = 32; off; off >>= 1) {
        d0 += __shfl_xor(d0, off);
        d1 += __shfl_xor(d1, off);
        d2 += __shfl_xor(d2, off);
        d3 += __shfl_xor(d3, off);
    }
    float dh   = h == 0 ? d0 : h == 1 ? d1 : h == 2 ? d2 : d3;
    float invh = dh > 0.f ? 1.f / dh : 0.f;
    accx *= invh; accy *= invh;

    int c = lane * 2;
    if (LAYER == 1) {
        float v0 = accx + bias[c];
        float v1 = accy + bias[c + 1];
        v0 = v0 > 0.f ? v0 : expm1f(v0);
        v1 = v1 > 0.f ? v1 : expm1f(v1);
        ((float2*)out)[(size_t)gw * 64 + lane] = make_float2(v0, v1);
    } else {
        float v0 = accx + bias[c];
        float v1 = accy + bias[c + 1];
        v0 += __shfl_xor(v0, 16); v0 += __shfl_xor(v0, 32);
        v1 += __shfl_xor(v1, 16); v1 += __shfl_xor(v1, 32);
        if (lane < 16)
            ((float2*)out)[(size_t)gw * 16 + lane] = make_float2(v0 * 0.25f, v1 * 0.25f);
    }
}

template __global__ void aggregate<1>(const float*, const float*, const float*,
                                      const int*, const int*, const float*, float*, int);
template __global__ void aggregate<2>(const float*, const float*, const float*,
                                      const int*, const int*, const float*, float*, int);

// ---------------- launcher ----------------
extern "C" void kernel_launch(void* const* d_in, const int* in_sizes, int n_in,
                              void* d_out, int out_size, void* d_ws, size_t ws_size,
                              hipStream_t stream)
{
    const float* X   = (const float*)d_in[0];
    const int*   src = (const int*)d_in[1];
    const int*   dst = (const int*)d_in[2];
    const float* W1  = (const float*)d_in[3];
    const float* al1 = (const float*)d_in[4];
    const float* ar1 = (const float*)d_in[5];
    const float* b1  = (const float*)d_in[6];
    const float* W2  = (const float*)d_in[7];
    const float* al2 = (const float*)d_in[8];
    const float* ar2 = (const float*)d_in[9];
    const float* b2  = (const float*)d_in[10];
    float* out = (float*)d_out;

    const int N = in_sizes[0] / 128;
    const int E = in_sizes[1];
    const int SB = (N + 1 + 1023) / 1024;

    size_t off = 0;
    char* base = (char*)d_ws;
    auto alloc = [&](size_t bytes) -> void* {
        void* p = base + off;
        off += (bytes + 255) & ~(size_t)255;
        return p;
    };
    float* feat   = (float*)alloc((size_t)N * 128 * 4);
    float* hbuf   = (float*)alloc((size_t)N * 128 * 4);
    float* el     = (float*)alloc((size_t)N * 4 * 4);
    float* er     = (float*)alloc((size_t)N * 4 * 4);
    int*   counts = (int*)alloc((size_t)N * 4);
    int*   offs   = (int*)alloc((size_t)(N + 1) * 4);
    int*   curs   = (int*)alloc((size_t)N * 4);
    int*   ssrc   = (int*)alloc((size_t)E * 4);
    int*   loc    = (int*)alloc((size_t)SB * 1024 * 4);
    int*   bsum   = (int*)alloc(64 * 4);
    int*   bout   = (int*)alloc(64 * 4);
    (void)ws_size; (void)n_in; (void)out_size;

    hipMemsetAsync(counts, 0, (size_t)N * 4, stream);

    // layer 1: GEMM + fused attention coefficients
    gemm_attn<<<(N + 31) / 32, 256, 0, stream>>>(X, W1, al1, ar1, feat, el, er, N);

    // CSR by destination (shared by both layers)
    hist_kernel<<<(E + 255) / 256, 256, 0, stream>>>(dst, counts, E);
    scan_block<<<SB, 1024, 0, stream>>>(counts, loc, bsum, N, N + 1);
    scan_tops<<<1, 64, 0, stream>>>(bsum, bout, SB);
    scan_add<<<SB, 1024, 0, stream>>>(loc, bout, offs, curs, N + 1, N);
    scatter_kernel<<<(E + 255) / 256, 256, 0, stream>>>(src, dst, curs, ssrc, E);

    // layer 1 aggregation -> elu(acc + b1) = hbuf [N,128]
    aggregate<1><<<(N + 3) / 4, 256, 0, stream>>>(feat, el, er, offs, ssrc, b1, hbuf, N);

    // layer 2
    gemm_attn<<<(N + 31) / 32, 256, 0, stream>>>(hbuf, W2, al2, ar2, feat, el, er, N);
    aggregate<2><<<(N + 3) / 4, 256, 0, stream>>>(feat, el, er, offs, ssrc, b2, out, N);
}